// Round 25
// baseline (1159.507 us; speedup 1.0000x reference)
//
#include <hip/hip_runtime.h>
#include <cfloat>
#include <cmath>

#define B_    64
#define C_    768
#define HW_   676
#define M_    32
#define TWOC_ 1536

// ---------------------------------------------------------------------------
// Stage 1: pool v2 -- fm[b,c,m] = max_hw f32(feat*attn).
// Coalesced float4 staging of feat+attn tiles (lanes sweep hw), compute from
// LDS. 128 thr = 64 c x 2 m-halves, acc[16]. Max is order-free -> bit-exact.
// ---------------------------------------------------------------------------
__global__ __launch_bounds__(128) void pool_kernel(
    const float* __restrict__ feat, const float* __restrict__ attn,
    float* __restrict__ fm)
{
    const int b      = blockIdx.x / 12;
    const int cchunk = blockIdx.x % 12;
    const int t  = threadIdx.x;      // 128
    const int cl = t >> 1;           // 0..63
    const int mh = (t & 1) * 16;     // 0 or 16

    __shared__ float a_s[32][68];    // [m][hw-local]
    __shared__ float f_s[64][68];    // [c-local][hw-local]

    float acc[16];
#pragma unroll
    for (int j = 0; j < 16; ++j) acc[j] = -FLT_MAX;

    const float* ap = attn + (size_t)b * M_ * HW_;
    const float* fp = feat + ((size_t)b * C_ + cchunk * 64) * HW_;

    for (int hw0 = 0; hw0 < HW_; hw0 += 64) {
        const int hwlen = min(64, HW_ - hw0);   // 64 or 36 (mult of 4)
        __syncthreads();
        for (int e = t; e < 512; e += 128) {    // attn: 32 m x 64 hw
            int m = e >> 4, hq = (e & 15) * 4;
            if (hq < hwlen)
                *(float4*)&a_s[m][hq] =
                    *(const float4*)(ap + (size_t)m * HW_ + hw0 + hq);
        }
        for (int e = t; e < 1024; e += 128) {   // feat: 64 c x 64 hw
            int r = e >> 4, hq = (e & 15) * 4;
            if (hq < hwlen)
                *(float4*)&f_s[r][hq] =
                    *(const float4*)(fp + (size_t)r * HW_ + hw0 + hq);
        }
        __syncthreads();
        for (int hw = 0; hw < hwlen; hw += 4) {
            float4 fv = *(const float4*)&f_s[cl][hw];
#pragma unroll
            for (int jm = 0; jm < 16; ++jm) {
                float4 av = *(const float4*)&a_s[mh + jm][hw];
                acc[jm] = fmaxf(acc[jm], __fmul_rn(fv.x, av.x));
                acc[jm] = fmaxf(acc[jm], __fmul_rn(fv.y, av.y));
                acc[jm] = fmaxf(acc[jm], __fmul_rn(fv.z, av.z));
                acc[jm] = fmaxf(acc[jm], __fmul_rn(fv.w, av.w));
            }
        }
    }
    float* op = fm + ((size_t)b * C_ + cchunk * 64 + cl) * M_ + mh;
#pragma unroll
    for (int j = 0; j < 4; ++j)
        *(float4*)(op + j * 4) = make_float4(acc[j*4+0], acc[j*4+1],
                                             acc[j*4+2], acc[j*4+3]);
}

// ---------------------------------------------------------------------------
// Stage 2: KNN -- MAJORITY VOTE across three noisy chemistries (VERIFIED
// PASSING in R22/R23/R24 -- ARITHMETIC FROZEN, DO NOT MODIFY):
// ---------------------------------------------------------------------------
__global__ __launch_bounds__(1024) void knn_kernel(
    const float* __restrict__ X, int* __restrict__ idxout)
{
    const int b = blockIdx.x;
    const int t = threadIdx.x;
    const int n = t >> 5, m = t & 31;

    __shared__ float xs[96][32];
    __shared__ float GF[32][32];   // mono fma inner
    __shared__ float G2[32][32];   // 2-panel inner
    __shared__ float XS[32];       // seq xx
    __shared__ float XP[32];       // pairwise xx
    __shared__ float PA[32][32], PC[32][32], PDm[32][32];

    const float* Xb = X + (size_t)b * (C_ * M_);
    float accF = 0.f;
    float accP0 = 0.f, accP1 = 0.f;
    float accXs = 0.f;
    float leaf[8];

#pragma unroll
    for (int chunk = 0; chunk < 8; ++chunk) {
        __syncthreads();
        for (int i = t; i < 96 * 32; i += 1024)
            xs[i >> 5][i & 31] = Xb[(size_t)(chunk * 96 + (i >> 5)) * M_ + (i & 31)];
        __syncthreads();
#pragma unroll
        for (int c = 0; c < 96; ++c)
            accF = __fmaf_rn(xs[c][n], xs[c][m], accF);
        if (chunk < 4) {
#pragma unroll
            for (int c = 0; c < 96; ++c)
                accP0 = __fmaf_rn(xs[c][n], xs[c][m], accP0);
        } else {
#pragma unroll
            for (int c = 0; c < 96; ++c)
                accP1 = __fmaf_rn(xs[c][n], xs[c][m], accP1);
        }
        if (t < 32) {
#pragma unroll
            for (int c = 0; c < 96; ++c) {
                float v = xs[c][m];
                accXs = __fadd_rn(accXs, __fmul_rn(v, v));
            }
            float r[8];
#pragma unroll
            for (int j = 0; j < 8; ++j) {
                float v = xs[j][m];
                r[j] = __fmul_rn(v, v);
            }
            for (int i = 8; i < 96; i += 8) {
#pragma unroll
                for (int j = 0; j < 8; ++j) {
                    float v = xs[i + j][m];
                    r[j] = __fadd_rn(r[j], __fmul_rn(v, v));
                }
            }
            leaf[chunk] = __fadd_rn(
                __fadd_rn(__fadd_rn(r[0], r[1]), __fadd_rn(r[2], r[3])),
                __fadd_rn(__fadd_rn(r[4], r[5]), __fadd_rn(r[6], r[7])));
        }
    }
    GF[n][m] = accF;
    G2[n][m] = __fadd_rn(accP0, accP1);
    if (t < 32) {
        XS[m] = accXs;
        XP[m] = __fadd_rn(
            __fadd_rn(__fadd_rn(leaf[0], leaf[1]), __fadd_rn(leaf[2], leaf[3])),
            __fadd_rn(__fadd_rn(leaf[4], leaf[5]), __fadd_rn(leaf[6], leaf[7])));
    }
    __syncthreads();
    PA[n][m]  = __fsub_rn(__fadd_rn(-XS[n], 2.0f * GF[n][m]), XS[m]);
    PC[n][m]  = __fsub_rn(__fadd_rn(-XP[n], 2.0f * G2[n][m]), XP[m]);
    PDm[n][m] = __fsub_rn(__fadd_rn(-XP[n], 2.0f * GF[n][m]), XP[m]);
    __syncthreads();

    if (t < 32) {
        const int nn = t;
        const float* pa = PA[nn];
        const float* pc = PC[nn];
        const float* pd = PDm[nn];

        unsigned masks[3] = {0u, 0u, 0u};
        const float* rows[3] = {pa, pc, pd};
#pragma unroll
        for (int s = 0; s < 3; ++s) {
            unsigned chosen = 0;
            for (int p = 0; p < 3; ++p) {
                float best = -FLT_MAX; int bi = 0;
                for (int mm = 0; mm < 32; ++mm) {
                    if (chosen & (1u << mm)) continue;
                    float v = rows[s][mm];
                    if (v > best) { best = v; bi = mm; }
                }
                chosen |= 1u << bi;
            }
            masks[s] = chosen;
        }
        const unsigned mA = masks[0], mC = masks[1], mD = masks[2];

        unsigned chosen = 0;
        for (int p = 0; p < 3; ++p) {
            int bv = -1; float bp = -FLT_MAX; int bi = 0;
            for (int mm = 0; mm < 32; ++mm) {
                if (chosen & (1u << mm)) continue;
                int v = (int)((mA >> mm) & 1u) + (int)((mC >> mm) & 1u)
                      + (int)((mD >> mm) & 1u);
                float q = pd[mm];
                if (v > bv || (v == bv && q > bp)) { bv = v; bp = q; bi = mm; }
            }
            chosen |= 1u << bi;
            idxout[((size_t)b * 32 + nn) * 3 + p] = bi;
        }
    }
}

// ---------------------------------------------------------------------------
// Stage 3+4 fused: conv v5 -- register-tiled mini-GEMM, o-tile 128.
// 256 thr: tx = nk-cols (s = tx+16q), ty x i = o = o0 + i*16 + ty.
// Per-output chain: mono sequential ascending-c fma (BIT-IDENTICAL to R24).
// ---------------------------------------------------------------------------
__global__ __launch_bounds__(256) void conv_kernel(
    const float* __restrict__ X, const float* __restrict__ W,
    const int* __restrict__ idx,
    const float* __restrict__ gamma, const float* __restrict__ beta,
    const float* __restrict__ mean,  const float* __restrict__ var,
    float* __restrict__ fout)
{
    const int b  = blockIdx.x / 6;
    const int oT = blockIdx.x % 6;
    const int o0 = oT * 128;
    const int t  = threadIdx.x;
    const int tx = t & 15;
    const int ty = t >> 4;        // 0..15

    __shared__ float fs_t[64][33];    // feature c-tile [cl][m]
    __shared__ float g_s[96][68];     // edge features [s=k*32+n][cl]
    __shared__ float w_s[128][68];    // weights [o-local][cl]
    __shared__ int   idx_s[96];

    if (t < 96) idx_s[t] = idx[b * 96 + t];

    float acc[8][6] = {};   // [i][q]

    const float* Xb = X + (size_t)b * (C_ * M_);

    for (int ct = 0; ct < 24; ++ct) {
        const int c0 = ct * 64;
        const bool diff = (c0 < C_);
        const int crow0 = diff ? c0 : (c0 - C_);
        __syncthreads();
        // stage feature tile (64 c x 32 m)
        for (int e = t; e < 512; e += 256) {
            int cl = e >> 3, mq = (e & 7) * 4;
            float4 v = *(const float4*)(Xb + (size_t)(crow0 + cl) * M_ + mq);
            fs_t[cl][mq + 0] = v.x; fs_t[cl][mq + 1] = v.y;
            fs_t[cl][mq + 2] = v.z; fs_t[cl][mq + 3] = v.w;
        }
        // stage weight tile (128 o x 64 c)
        for (int e = t; e < 2048; e += 256) {
            int o = e >> 4, cq = (e & 15) * 4;
            float4 v = *(const float4*)(W + (size_t)(o0 + o) * TWOC_ + c0 + cq);
            *(float4*)&w_s[o][cq] = v;
        }
        __syncthreads();
        // build g tile: s = k*32+n
        for (int e = t; e < 96 * 64; e += 256) {
            int s = e >> 6, cl = e & 63;
            int n = s & 31, k = s >> 5;
            float v;
            if (diff) {
                int j = idx_s[n * 3 + k];
                v = __fsub_rn(fs_t[cl][j], fs_t[cl][n]);
            } else {
                v = fs_t[cl][n];
            }
            g_s[s][cl] = v;
        }
        __syncthreads();
        // FMA: 16 x (8 w-b128 + 6 g-b128 -> 192 fma)
        for (int c4 = 0; c4 < 64; c4 += 4) {
            float4 gv[6];
#pragma unroll
            for (int q = 0; q < 6; ++q)
                gv[q] = *(const float4*)&g_s[tx + 16 * q][c4];
#pragma unroll
            for (int i = 0; i < 8; ++i) {
                float4 wv = *(const float4*)&w_s[i * 16 + ty][c4];
#pragma unroll
                for (int q = 0; q < 6; ++q) {
                    float a = acc[i][q];
                    a = __fmaf_rn(wv.x, gv[q].x, a);
                    a = __fmaf_rn(wv.y, gv[q].y, a);
                    a = __fmaf_rn(wv.z, gv[q].z, a);
                    a = __fmaf_rn(wv.w, gv[q].w, a);
                    acc[i][q] = a;
                }
            }
        }
    }

    // epilogue: q -> (n = tx + 16*(q&1), k = q>>1); BN + leaky + k-max.
#pragma unroll
    for (int i = 0; i < 8; ++i) {
        const int o = o0 + i * 16 + ty;
        const float sc = __fdiv_rn(gamma[o], __fsqrt_rn(__fadd_rn(var[o], 1e-5f)));
        const float mu = mean[o], be = beta[o];
#pragma unroll
        for (int half = 0; half < 2; ++half) {
            const int n = tx + 16 * half;
            float r = -FLT_MAX;
#pragma unroll
            for (int k = 0; k < 3; ++k) {
                float y = acc[i][2 * k + half];
                y = __fadd_rn(__fmul_rn(__fsub_rn(y, mu), sc), be);
                y = (y >= 0.f) ? y : __fmul_rn(0.2f, y);
                r = fmaxf(r, y);
            }
            fout[((size_t)b * C_ + o) * M_ + n] = r;
        }
    }
}

// ---------------------------------------------------------------------------
// Stage 5: fuse -- f32-faithful per-element; norm reduction in f64.
// ---------------------------------------------------------------------------
__global__ __launch_bounds__(256) void fuse_kernel(
    const float* __restrict__ f1, const float* __restrict__ f2,
    float* __restrict__ out)
{
    const int b = blockIdx.x;
    const int t = threadIdx.x;
    const float* p1 = f1 + (size_t)b * (C_ * M_);
    const float* p2 = f2 + (size_t)b * (C_ * M_);
    float* po = out + (size_t)b * (2 * C_ * M_);

    __shared__ double red[256];

    double lsum = 0.0;
    for (int i = t; i < 2 * C_ * M_; i += 256) {
        float x = (i < C_ * M_) ? p1[i] : p2[i - C_ * M_];
        float sq = __fsqrt_rn(__fadd_rn(fabsf(x), 1e-12f));
        float s = (x > 0.f) ? sq : ((x < 0.f) ? -sq : 0.f);
        lsum += (double)s * (double)s;
    }
    red[t] = lsum;
    __syncthreads();
    for (int off = 128; off > 0; off >>= 1) {
        if (t < off) red[t] += red[t + off];
        __syncthreads();
    }
    const float normf = fmaxf((float)sqrt(red[0]), 1e-12f);
    for (int i = t; i < 2 * C_ * M_; i += 256) {
        float x = (i < C_ * M_) ? p1[i] : p2[i - C_ * M_];
        float sq = __fsqrt_rn(__fadd_rn(fabsf(x), 1e-12f));
        float s = (x > 0.f) ? sq : ((x < 0.f) ? -sq : 0.f);
        po[i] = __fdiv_rn(s, normf);
    }
}

// ---------------------------------------------------------------------------
extern "C" void kernel_launch(void* const* d_in, const int* in_sizes, int n_in,
                              void* d_out, int out_size, void* d_ws, size_t ws_size,
                              hipStream_t stream)
{
    const float* feat = (const float*)d_in[0];
    const float* attn = (const float*)d_in[1];
    const float* W1   = (const float*)d_in[2];
    const float* g1   = (const float*)d_in[3];
    const float* be1  = (const float*)d_in[4];
    const float* mu1  = (const float*)d_in[5];
    const float* va1  = (const float*)d_in[6];
    const float* W2   = (const float*)d_in[7];
    const float* g2   = (const float*)d_in[8];
    const float* be2  = (const float*)d_in[9];
    const float* mu2  = (const float*)d_in[10];
    const float* va2  = (const float*)d_in[11];

    const size_t FM = (size_t)B_ * C_ * M_;       // 1,572,864 elements
    float* fm  = (float*)d_ws;
    float* f1  = fm + FM;
    float* f2  = f1 + FM;
    int* idx1  = (int*)(f2 + FM);
    int* idx2  = idx1 + B_ * M_ * 3;

    pool_kernel<<<dim3(768), dim3(128), 0, stream>>>(feat, attn, fm);
    knn_kernel<<<dim3(64), dim3(1024), 0, stream>>>(fm, idx1);
    conv_kernel<<<dim3(384), dim3(256), 0, stream>>>(fm, W1, idx1, g1, be1, mu1, va1, f1);
    knn_kernel<<<dim3(64), dim3(1024), 0, stream>>>(f1, idx2);
    conv_kernel<<<dim3(384), dim3(256), 0, stream>>>(f1, W2, idx2, g2, be2, mu2, va2, f2);
    fuse_kernel<<<dim3(64), dim3(256), 0, stream>>>(f1, f2, (float*)d_out);
}